// Round 16
// baseline (94.134 us; speedup 1.0000x reference)
//
#include <hip/hip_runtime.h>
#include <hip/hip_bf16.h>
#include <cstdint>
#include <cstddef>

typedef short bf16x8 __attribute__((ext_vector_type(8)));
typedef short bf16x4 __attribute__((ext_vector_type(4)));
typedef float f32x4  __attribute__((ext_vector_type(4)));

#define MFMA16(A, B, C) __builtin_amdgcn_mfma_f32_16x16x32_bf16(A, B, C, 0, 0, 0)

constexpr int XSTR = 1032;   // u16 row stride per sample strip in xs (2064 B)
constexpr int BSTR = 520;    // u16 per-sample stride in fbuf (1040 B, 16B-aligned)
constexpr size_t WS_FC   = (size_t)2176 * 1024;
constexpr size_t WS_BOTH = WS_FC + (size_t)576 * 1024;

__device__ __forceinline__ unsigned short f2bf(float x) {
    unsigned u = __float_as_uint(x);
    unsigned r = u + 0x7fffu + ((u >> 16) & 1u);
    return (unsigned short)(r >> 16);
}
__device__ __forceinline__ float bf2f(unsigned short h) {
    return __uint_as_float(((unsigned)h) << 16);
}
// hardware v_cvt_pk_bf16_f32 (RNE) — same rounding as f2bf
__device__ __forceinline__ unsigned pkbf(float a, float b) {
    __hip_bfloat162 h = __float22bfloat162_rn(make_float2(a, b));
    return *reinterpret_cast<unsigned*>(&h);
}
__device__ __forceinline__ bf16x8 load8_f32(const float* __restrict__ s) {
    float4 a = *(const float4*)s;
    float4 b = *(const float4*)(s + 4);
    bf16x8 r;
    r[0]=(short)f2bf(a.x); r[1]=(short)f2bf(a.y); r[2]=(short)f2bf(a.z); r[3]=(short)f2bf(a.w);
    r[4]=(short)f2bf(b.x); r[5]=(short)f2bf(b.y); r[6]=(short)f2bf(b.z); r[7]=(short)f2bf(b.w);
    return r;
}

// FC B-frag: lane element j = Wfc[ntile*16+(lane&15)][kg*32+(lane>>4)*8+j]
template<int MODE>
__device__ __forceinline__ bf16x8 fc_bfrag(const unsigned short* __restrict__ wfcb,
                                           const float* __restrict__ Wfc,
                                           int kg, int ntile, int lane)
{
    if constexpr (MODE >= 1) {
        return *(const bf16x8*)(wfcb + (((size_t)(kg * 8 + ntile)) << 9) + lane * 8);
    } else {
        const float* s = Wfc + (size_t)(ntile * 16 + (lane & 15)) * 8704
                             + kg * 32 + (lane >> 4) * 8;
        return load8_f32(s);
    }
}
// hconv B-frag: k = kstep*32+(lane>>4)*8+j -> Wh[H-1][ntile*16+(lane&15)][k>>7][k&127]
template<int MODE>
__device__ __forceinline__ bf16x8 wh_bfrag(const unsigned short* __restrict__ whb,
                                           const float* __restrict__ Wh,
                                           int H, int kstep, int ntile, int lane)
{
    if constexpr (MODE == 2) {
        return *(const bf16x8*)(whb +
            (((size_t)(8 * H * (H - 1) + kstep * 4 + ntile)) << 9) + lane * 8);
    } else {
        const int k = kstep * 32 + (lane >> 4) * 8;
        const float* s = Wh + ((((size_t)(H - 1) * 64 + ntile * 16 + (lane & 15)) * 8
                               + (k >> 7)) * 128 + (k & 127));
        return load8_f32(s);
    }
}

// prep = run the direct loader once per frag, store result (packed == direct)
__global__ __launch_bounds__(256)
void caser_prep(const float* __restrict__ Wfc, const float* __restrict__ Wh,
                unsigned short* __restrict__ wfcb, unsigned short* __restrict__ whb,
                int nfrag)
{
    const int tid = blockIdx.x * 256 + threadIdx.x;
    const int lane = tid & 63, frag = tid >> 6;
    if (frag >= nfrag) return;
    if (frag < 2176) {
        const int kg = frag >> 3, nt = frag & 7;
        bf16x8 v = fc_bfrag<0>(nullptr, Wfc, kg, nt, lane);
        *(bf16x8*)(wfcb + ((size_t)frag << 9) + lane * 8) = v;
    } else {
        const int f2 = frag - 2176;
        int h = 1;
        while (f2 >= 8 * h * (h + 1)) ++h;
        const int fl = f2 - 8 * h * (h - 1);
        const int nt = fl & 3, kstep = fl >> 2;
        bf16x8 v = wh_bfrag<0>(nullptr, Wh, h, kstep, nt, lane);
        *(bf16x8*)(whb + ((size_t)f2 << 9) + lane * 8) = v;
    }
}

// ===================== hconv MFMA (one h, one filter-16-group, one j-parity) =
// D[sample=(lane>>4)*4+r][filter_local=lane&15]  (R6-R12 validated)
template<int H, int PP, int MODE>
__device__ __forceinline__ void hconv_compute(
    const unsigned short* __restrict__ xs,
    const unsigned short* __restrict__ whb, const float* __restrict__ Wh,
    const float* __restrict__ bh,
    int m, int nt4, int lane, int laneA, float mx[4])
{
    constexpr int NJ = 9 - H;
    constexpr int NJS = (PP == 0) ? ((NJ + 1) / 2) : (NJ / 2);
    if constexpr (NJS > 0) {
        f32x4 C[NJS] = {};
        const unsigned short* xbase = xs + m * 16 * XSTR + laneA;
        #pragma unroll
        for (int kstep = 0; kstep < 4 * H; ++kstep) {
            const int hp = kstep >> 2, d0 = (kstep & 3) * 32;
            bf16x8 B = wh_bfrag<MODE>(whb, Wh, H, kstep, nt4, lane);
            #pragma unroll
            for (int idx = 0; idx < NJS; ++idx) {
                const int j = PP + 2 * idx;
                bf16x8 A = *(const bf16x8*)(xbase + (j + hp) * 128 + d0);
                C[idx] = MFMA16(A, B, C[idx]);
            }
        }
        const float bhv = bh[(H - 1) * 64 + nt4 * 16 + (lane & 15)];
        #pragma unroll
        for (int idx = 0; idx < NJS; ++idx)
            #pragma unroll
            for (int r = 0; r < 4; ++r)
                mx[r] = fmaxf(mx[r], fmaxf(C[idx][r] + bhv, 0.f));
    }
}

// paired h-steps: compute hconv for H and H+1 back-to-back (independent MFMA
// chains + load streams), then store/merge each with one barrier apiece.
// Buffer lifetimes match R12's alternation exactly:
//   candA's last reader (merge_H) precedes the pair's 2nd barrier; candA's
//   next writer is the NEXT pair's store, after that barrier -> safe.
template<int H1, int MODE>
__device__ __forceinline__ void hpair(
    const unsigned short* __restrict__ xs, unsigned short* __restrict__ feat,
    float* __restrict__ candA, float* __restrict__ candB,
    const unsigned short* __restrict__ whb, const float* __restrict__ Wh,
    const float* __restrict__ bh,
    int t, int lane, int laneA, int hm, int hn4, int pj)
{
    float mxa[4] = {}, mxb[4] = {};
    if (pj == 0) {
        hconv_compute<H1,     0, MODE>(xs, whb, Wh, bh, hm, hn4, lane, laneA, mxa);
        hconv_compute<H1 + 1, 0, MODE>(xs, whb, Wh, bh, hm, hn4, lane, laneA, mxb);
    } else {
        hconv_compute<H1,     1, MODE>(xs, whb, Wh, bh, hm, hn4, lane, laneA, mxa);
        hconv_compute<H1 + 1, 1, MODE>(xs, whb, Wh, bh, hm, hn4, lane, laneA, mxb);
    }
    const int crow = pj * 2176 + (hm * 16 + (lane >> 4) * 4) * 68 + hn4 * 16 + (lane & 15);
    #pragma unroll
    for (int r = 0; r < 4; ++r) candA[crow + r * 68] = mxa[r];
    __syncthreads();
    {   // merge H1 -> feat col (H1-1)*64
        const int s = t >> 5, f0 = (t & 31) * 2;
        float a0 = fmaxf(candA[s * 68 + f0],     candA[2176 + s * 68 + f0]);
        float a1 = fmaxf(candA[s * 68 + f0 + 1], candA[2176 + s * 68 + f0 + 1]);
        *(unsigned*)(feat + s * BSTR + (H1 - 1) * 64 + f0) = pkbf(a0, a1);
    }
    #pragma unroll
    for (int r = 0; r < 4; ++r) candB[crow + r * 68] = mxb[r];
    __syncthreads();
    {   // merge H1+1 -> feat col H1*64
        const int s = t >> 5, f0 = (t & 31) * 2;
        float a0 = fmaxf(candB[s * 68 + f0],     candB[2176 + s * 68 + f0]);
        float a1 = fmaxf(candB[s * 68 + f0 + 1], candB[2176 + s * 68 + f0 + 1]);
        *(unsigned*)(feat + s * BSTR + H1 * 64 + f0) = pkbf(a0, a1);
    }
    // no trailing barrier (next pair's compute touches only xs/whb)
}

// ============================ main fused kernel ==============================
template<int MODE>
__global__ __launch_bounds__(1024, 1)
void caser_main(const int* __restrict__ user_id,
                const int* __restrict__ seq,
                const int* __restrict__ item_id,
                const float* __restrict__ Q,
                const float* __restrict__ Pmat,
                const float* __restrict__ Qp,
                const float* __restrict__ b_item,
                const float* __restrict__ Wv,
                const float* __restrict__ bv,
                const float* __restrict__ Wh,
                const float* __restrict__ bh,
                const float* __restrict__ Wfc,
                const float* __restrict__ bfc,
                const unsigned short* __restrict__ wfcb,
                const unsigned short* __restrict__ whb,
                float* __restrict__ out)
{
    __shared__ unsigned short xs[32 * XSTR];       // 66048 B  x = Q[seq] / zbuf4
    __shared__ unsigned short fbuf[2 * 32 * BSTR]; // 66560 B  ping-pong / candB
    __shared__ float cand[2 * 32 * 68];            // 17408 B  hconv candA
    __shared__ float wv_s[576];                    //  2304 B  Wv + bv

    const int t = threadIdx.x;
    const int lane = t & 63;
    const int w = t >> 6;                  // 0..15
    const int b0 = blockIdx.x * 32;
    const int laneA = (lane & 15) * XSTR + (lane >> 4) * 8;
    const int laneB = (lane & 15) * BSTR + (lane >> 4) * 8;
    // FC split: 4 K-quarters x 4 N-groups
    const int kh = w & 3, ng = w >> 2;
    // hconv split: sample-half x filter-16-group x j-parity
    const int hm = w & 1, hn4 = (w >> 1) & 3, pj = (w >> 3) & 1;

    // ---------------- phase 0: weights + x gather ----------------
    if (t < 576) wv_s[t] = (t < 512) ? Wv[t] : bv[t - 512];   // 1024 >= 576: safe
    #pragma unroll
    for (int k = 0; k < 8; ++k) {
        const int idx = t + k * 1024;       // 0..8191 chunks of 4 floats
        const int i = idx & 31;
        const int l = (idx >> 5) & 7;
        const int s = idx >> 8;
        const int it = seq[(b0 + s) * 8 + l];
        float4 v = *(const float4*)(Q + (size_t)it * 128 + i * 4);
        uint2 pk;
        pk.x = pkbf(v.x, v.y);
        pk.y = pkbf(v.z, v.w);
        *(uint2*)(xs + s * XSTR + l * 128 + i * 4) = pk;
    }
    __syncthreads();

    // vconv x slice -> regs: thread (sv=t>>5, dq=t&31) owns d = dq*4..+3
    const int sv = t >> 5, dq = t & 31;
    float xr[8][4];
    #pragma unroll
    for (int l = 0; l < 8; ++l) {
        bf16x4 v = *(const bf16x4*)(xs + sv * XSTR + l * 128 + dq * 4);
        #pragma unroll
        for (int i = 0; i < 4; ++i) xr[l][i] = bf2f((unsigned short)v[i]);
    }

    f32x4 FCC[2][2] = {};

    // ---------------- phase 1: vconv ∥ FC, ping-pong + B-prefetch ---------
    uint2 vc[4];
    #define VCONV_HALF(hc_)                                                    \
        {                                                                      \
            _Pragma("unroll")                                                  \
            for (int fl = 0; fl < 4; ++fl) {                                   \
                const int f = (hc_) * 4 + fl;                                  \
                const float bvv = wv_s[512 + f];                               \
                float acc[4];                                                  \
                _Pragma("unroll")                                              \
                for (int i = 0; i < 4; ++i) acc[i] = bvv;                      \
                _Pragma("unroll")                                              \
                for (int l = 0; l < 8; ++l) {                                  \
                    const float wl = wv_s[f * 8 + l];                          \
                    _Pragma("unroll")                                          \
                    for (int i = 0; i < 4; ++i)                                \
                        acc[i] = fmaf(xr[l][i], wl, acc[i]);                   \
                }                                                              \
                vc[fl].x = pkbf(fmaxf(acc[0], 0.f), fmaxf(acc[1], 0.f));       \
                vc[fl].y = pkbf(fmaxf(acc[2], 0.f), fmaxf(acc[3], 0.f));       \
            }                                                                  \
        }
    #define VSTORE(buf_)                                                       \
        {                                                                      \
            unsigned short* fb = fbuf + (buf_) * (32 * BSTR);                  \
            _Pragma("unroll")                                                  \
            for (int fl = 0; fl < 4; ++fl)                                     \
                *(uint2*)(fb + sv * BSTR + fl * 128 + dq * 4) = vc[fl];        \
        }

    bf16x8 BF0[4], BF1[4];
    #pragma unroll
    for (int ks = 0; ks < 4; ++ks) {
        const int kg = kh * 4 + ks;
        BF0[ks] = fc_bfrag<MODE>(wfcb, Wfc, kg, ng * 2,     lane);
        BF1[ks] = fc_bfrag<MODE>(wfcb, Wfc, kg, ng * 2 + 1, lane);
    }
    VCONV_HALF(0);
    VSTORE(0);
    __syncthreads();

    #pragma unroll 1
    for (int hc = 0; hc < 16; ++hc) {
        {   // FC on buf hc&1 using prefetched B-frags
            const unsigned short* fb = fbuf + (hc & 1) * (32 * BSTR);
            #pragma unroll
            for (int ks = 0; ks < 4; ++ks) {
                const int kl = kh * 4 + ks;
                bf16x8 A0 = *(const bf16x8*)(fb + laneB + kl * 32);
                bf16x8 A1 = *(const bf16x8*)(fb + 16 * BSTR + laneB + kl * 32);
                FCC[0][0] = MFMA16(A0, BF0[ks], FCC[0][0]);
                FCC[0][1] = MFMA16(A0, BF1[ks], FCC[0][1]);
                FCC[1][0] = MFMA16(A1, BF0[ks], FCC[1][0]);
                FCC[1][1] = MFMA16(A1, BF1[ks], FCC[1][1]);
            }
        }
        if (hc < 15) {
            // issue next iteration's B-frag loads; latency covered by
            // vconv VALU + VSTORE + the barrier's vmcnt(0) drain
            #pragma unroll
            for (int ks = 0; ks < 4; ++ks) {
                const int kg = (hc + 1) * 16 + kh * 4 + ks;
                BF0[ks] = fc_bfrag<MODE>(wfcb, Wfc, kg, ng * 2,     lane);
                BF1[ks] = fc_bfrag<MODE>(wfcb, Wfc, kg, ng * 2 + 1, lane);
            }
            VCONV_HALF(hc + 1);
            VSTORE((hc + 1) & 1);
        }
        __syncthreads();
    }
    #undef VCONV_HALF
    #undef VSTORE

    // ---------------- phase 2: MFMA hconv h=1..8, paired -> feat[32][512] -
    unsigned short* feat = fbuf;                      // buffer 0, cols 0..511
    float* candA = cand;
    float* candB = (float*)(fbuf + 32 * BSTR);        // dead buffer 1 (33 KB)
    hpair<1, MODE>(xs, feat, candA, candB, whb, Wh, bh, t, lane, laneA, hm, hn4, pj);
    hpair<3, MODE>(xs, feat, candA, candB, whb, Wh, bh, t, lane, laneA, hm, hn4, pj);
    hpair<5, MODE>(xs, feat, candA, candB, whb, Wh, bh, t, lane, laneA, hm, hn4, pj);
    hpair<7, MODE>(xs, feat, candA, candB, whb, Wh, bh, t, lane, laneA, hm, hn4, pj);

    // prefetch final-FC B-frags ahead of the barrier
    #pragma unroll
    for (int kgi = 0; kgi < 4; ++kgi) {
        const int kg = 256 + kh * 4 + kgi;
        BF0[kgi] = fc_bfrag<MODE>(wfcb, Wfc, kg, ng * 2,     lane);
        BF1[kgi] = fc_bfrag<MODE>(wfcb, Wfc, kg, ng * 2 + 1, lane);
    }
    __syncthreads();   // all feat columns written

    // single FC pass over hconv K=512 (kg = 256..271)
    #pragma unroll
    for (int kgi = 0; kgi < 4; ++kgi) {
        const int kloc = kh * 4 + kgi;               // 0..15
        bf16x8 A0 = *(const bf16x8*)(feat + laneB + kloc * 32);
        bf16x8 A1 = *(const bf16x8*)(feat + 16 * BSTR + laneB + kloc * 32);
        FCC[0][0] = MFMA16(A0, BF0[kgi], FCC[0][0]);
        FCC[0][1] = MFMA16(A0, BF1[kgi], FCC[0][1]);
        FCC[1][0] = MFMA16(A1, BF0[kgi], FCC[1][0]);
        FCC[1][1] = MFMA16(A1, BF1[kgi], FCC[1][1]);
    }

    // ---------------- epilogue: 4-quarter merge, relu, score --------------
    float* zbuf4 = (float*)xs;   // [4][32][132] overlay on dead xs (67584 B)
    #pragma unroll
    for (int m = 0; m < 2; ++m)
        #pragma unroll
        for (int nt = 0; nt < 2; ++nt)
            #pragma unroll
            for (int r = 0; r < 4; ++r)
                zbuf4[kh * (32 * 132) + (m * 16 + (lane >> 4) * 4 + r) * 132 +
                      ng * 32 + nt * 16 + (lane & 15)] = FCC[m][nt][r];
    __syncthreads();
    {
        const int s = t >> 5, l32 = t & 31, o0 = l32 * 4;
        const int b = b0 + s;
        const int item = item_id[b];
        const int user = user_id[b];
        const float* qp = Qp + (size_t)item * 256;
        const float* pu = Pmat + (size_t)user * 128;
        float acc2 = 0.f;
        #pragma unroll
        for (int i = 0; i < 4; ++i) {
            float z = zbuf4[s * 132 + o0 + i]
                    + zbuf4[1 * (32 * 132) + s * 132 + o0 + i]
                    + zbuf4[2 * (32 * 132) + s * 132 + o0 + i]
                    + zbuf4[3 * (32 * 132) + s * 132 + o0 + i]
                    + bfc[o0 + i];
            z = fmaxf(z, 0.f);
            acc2 = fmaf(z, qp[o0 + i], acc2);
        }
        #pragma unroll
        for (int i = 0; i < 4; ++i)
            acc2 = fmaf(pu[o0 + i], qp[128 + o0 + i], acc2);
        acc2 += __shfl_xor(acc2, 1, 32);
        acc2 += __shfl_xor(acc2, 2, 32);
        acc2 += __shfl_xor(acc2, 4, 32);
        acc2 += __shfl_xor(acc2, 8, 32);
        acc2 += __shfl_xor(acc2, 16, 32);
        if (l32 == 0) out[b] = acc2 + b_item[item];
    }
}

extern "C" void kernel_launch(void* const* d_in, const int* in_sizes, int n_in,
                              void* d_out, int out_size, void* d_ws, size_t ws_size,
                              hipStream_t stream)
{
    const int*   user_id = (const int*)  d_in[0];
    const int*   seq     = (const int*)  d_in[1];
    const int*   item_id = (const int*)  d_in[2];
    const float* Q       = (const float*)d_in[3];
    const float* Pmat    = (const float*)d_in[4];
    const float* Qp      = (const float*)d_in[5];
    const float* b_item  = (const float*)d_in[6];
    const float* Wv      = (const float*)d_in[7];
    const float* bv      = (const float*)d_in[8];
    const float* Wh      = (const float*)d_in[9];
    const float* bh      = (const float*)d_in[10];
    const float* Wfc     = (const float*)d_in[11];
    const float* bfc     = (const float*)d_in[12];
    float* out = (float*)d_out;

    unsigned short* wfcb = (unsigned short*)d_ws;
    unsigned short* whb  = wfcb + WS_FC / 2;

    if (ws_size >= WS_BOTH) {
        hipLaunchKernelGGL(caser_prep, dim3(688), dim3(256), 0, stream,
                           Wfc, Wh, wfcb, whb, 2752);
        hipLaunchKernelGGL((caser_main<2>), dim3(256), dim3(1024), 0, stream,
                           user_id, seq, item_id, Q, Pmat, Qp, b_item,
                           Wv, bv, Wh, bh, Wfc, bfc, wfcb, whb, out);
    } else if (ws_size >= WS_FC) {
        hipLaunchKernelGGL(caser_prep, dim3(544), dim3(256), 0, stream,
                           Wfc, Wh, wfcb, whb, 2176);
        hipLaunchKernelGGL((caser_main<1>), dim3(256), dim3(1024), 0, stream,
                           user_id, seq, item_id, Q, Pmat, Qp, b_item,
                           Wv, bv, Wh, bh, Wfc, bfc, wfcb, whb, out);
    } else {
        hipLaunchKernelGGL((caser_main<0>), dim3(256), dim3(1024), 0, stream,
                           user_id, seq, item_id, Q, Pmat, Qp, b_item,
                           Wv, bv, Wh, bh, Wfc, bfc,
                           (const unsigned short*)nullptr, (const unsigned short*)nullptr, out);
    }
}

// Round 17
// 77.978 us; speedup vs baseline: 1.2072x; 1.2072x over previous
//
#include <hip/hip_runtime.h>
#include <hip/hip_bf16.h>
#include <cstdint>
#include <cstddef>

typedef short bf16x8 __attribute__((ext_vector_type(8)));
typedef short bf16x4 __attribute__((ext_vector_type(4)));
typedef float f32x4  __attribute__((ext_vector_type(4)));

#define MFMA16(A, B, C) __builtin_amdgcn_mfma_f32_16x16x32_bf16(A, B, C, 0, 0, 0)

constexpr int XSTR = 1032;   // u16 row stride per sample strip in xs (2064 B)
constexpr int BSTR = 520;    // u16 per-sample stride in fbuf (1040 B, 16B-aligned)
constexpr size_t WS_FC   = (size_t)2176 * 1024;
constexpr size_t WS_BOTH = WS_FC + (size_t)576 * 1024;

__device__ __forceinline__ unsigned short f2bf(float x) {
    unsigned u = __float_as_uint(x);
    unsigned r = u + 0x7fffu + ((u >> 16) & 1u);
    return (unsigned short)(r >> 16);
}
__device__ __forceinline__ float bf2f(unsigned short h) {
    return __uint_as_float(((unsigned)h) << 16);
}
// hardware v_cvt_pk_bf16_f32 (RNE) — same rounding as f2bf
__device__ __forceinline__ unsigned pkbf(float a, float b) {
    __hip_bfloat162 h = __float22bfloat162_rn(make_float2(a, b));
    return *reinterpret_cast<unsigned*>(&h);
}
__device__ __forceinline__ bf16x8 load8_f32(const float* __restrict__ s) {
    float4 a = *(const float4*)s;
    float4 b = *(const float4*)(s + 4);
    bf16x8 r;
    r[0]=(short)f2bf(a.x); r[1]=(short)f2bf(a.y); r[2]=(short)f2bf(a.z); r[3]=(short)f2bf(a.w);
    r[4]=(short)f2bf(b.x); r[5]=(short)f2bf(b.y); r[6]=(short)f2bf(b.z); r[7]=(short)f2bf(b.w);
    return r;
}

// FC B-frag: lane element j = Wfc[ntile*16+(lane&15)][kg*32+(lane>>4)*8+j]
template<int MODE>
__device__ __forceinline__ bf16x8 fc_bfrag(const unsigned short* __restrict__ wfcb,
                                           const float* __restrict__ Wfc,
                                           int kg, int ntile, int lane)
{
    if constexpr (MODE >= 1) {
        return *(const bf16x8*)(wfcb + (((size_t)(kg * 8 + ntile)) << 9) + lane * 8);
    } else {
        const float* s = Wfc + (size_t)(ntile * 16 + (lane & 15)) * 8704
                             + kg * 32 + (lane >> 4) * 8;
        return load8_f32(s);
    }
}
// hconv B-frag: k = kstep*32+(lane>>4)*8+j -> Wh[H-1][ntile*16+(lane&15)][k>>7][k&127]
template<int MODE>
__device__ __forceinline__ bf16x8 wh_bfrag(const unsigned short* __restrict__ whb,
                                           const float* __restrict__ Wh,
                                           int H, int kstep, int ntile, int lane)
{
    if constexpr (MODE == 2) {
        return *(const bf16x8*)(whb +
            (((size_t)(8 * H * (H - 1) + kstep * 4 + ntile)) << 9) + lane * 8);
    } else {
        const int k = kstep * 32 + (lane >> 4) * 8;
        const float* s = Wh + ((((size_t)(H - 1) * 64 + ntile * 16 + (lane & 15)) * 8
                               + (k >> 7)) * 128 + (k & 127));
        return load8_f32(s);
    }
}

// prep = run the direct loader once per frag, store result (packed == direct)
__global__ __launch_bounds__(256)
void caser_prep(const float* __restrict__ Wfc, const float* __restrict__ Wh,
                unsigned short* __restrict__ wfcb, unsigned short* __restrict__ whb,
                int nfrag)
{
    const int tid = blockIdx.x * 256 + threadIdx.x;
    const int lane = tid & 63, frag = tid >> 6;
    if (frag >= nfrag) return;
    if (frag < 2176) {
        const int kg = frag >> 3, nt = frag & 7;
        bf16x8 v = fc_bfrag<0>(nullptr, Wfc, kg, nt, lane);
        *(bf16x8*)(wfcb + ((size_t)frag << 9) + lane * 8) = v;
    } else {
        const int f2 = frag - 2176;
        int h = 1;
        while (f2 >= 8 * h * (h + 1)) ++h;
        const int fl = f2 - 8 * h * (h - 1);
        const int nt = fl & 3, kstep = fl >> 2;
        bf16x8 v = wh_bfrag<0>(nullptr, Wh, h, kstep, nt, lane);
        *(bf16x8*)(whb + ((size_t)f2 << 9) + lane * 8) = v;
    }
}

// ===================== hconv MFMA (one h, one filter-16-group, one j-parity) =
// D[sample=(lane>>4)*4+r][filter_local=lane&15]  (R6-R12 validated)
template<int H, int PP, int MODE>
__device__ __forceinline__ void hconv_compute(
    const unsigned short* __restrict__ xs,
    const unsigned short* __restrict__ whb, const float* __restrict__ Wh,
    const float* __restrict__ bh,
    int m, int nt4, int lane, int laneA, float mx[4])
{
    constexpr int NJ = 9 - H;
    constexpr int NJS = (PP == 0) ? ((NJ + 1) / 2) : (NJ / 2);
    if constexpr (NJS > 0) {
        f32x4 C[NJS] = {};
        const unsigned short* xbase = xs + m * 16 * XSTR + laneA;
        #pragma unroll
        for (int kstep = 0; kstep < 4 * H; ++kstep) {
            const int hp = kstep >> 2, d0 = (kstep & 3) * 32;
            bf16x8 B = wh_bfrag<MODE>(whb, Wh, H, kstep, nt4, lane);
            #pragma unroll
            for (int idx = 0; idx < NJS; ++idx) {
                const int j = PP + 2 * idx;
                bf16x8 A = *(const bf16x8*)(xbase + (j + hp) * 128 + d0);
                C[idx] = MFMA16(A, B, C[idx]);
            }
        }
        const float bhv = bh[(H - 1) * 64 + nt4 * 16 + (lane & 15)];
        #pragma unroll
        for (int idx = 0; idx < NJS; ++idx)
            #pragma unroll
            for (int r = 0; r < 4; ++r)
                mx[r] = fmaxf(mx[r], fmaxf(C[idx][r] + bhv, 0.f));
    }
}

// one h-step: hconv MFMA -> parity merge (alternating cand buffer) ->
// feat column (H-1)*64. ONE barrier per step (cand_h reused only at h+2,
// and merge_h precedes BAR_{h+1} in program order -> safe).
template<int H, int MODE>
__device__ __forceinline__ void hstep(
    const unsigned short* __restrict__ xs, unsigned short* __restrict__ feat,
    float* __restrict__ candc,
    const unsigned short* __restrict__ whb, const float* __restrict__ Wh,
    const float* __restrict__ bh,
    int t, int lane, int laneA, int hm, int hn4, int pj)
{
    float mx[4] = {};
    if (pj == 0) hconv_compute<H, 0, MODE>(xs, whb, Wh, bh, hm, hn4, lane, laneA, mx);
    else         hconv_compute<H, 1, MODE>(xs, whb, Wh, bh, hm, hn4, lane, laneA, mx);
    #pragma unroll
    for (int r = 0; r < 4; ++r)
        candc[pj * 2176 + (hm * 16 + (lane >> 4) * 4 + r) * 68 +
              hn4 * 16 + (lane & 15)] = mx[r];
    __syncthreads();
    {   // merge 2 parity candidates -> 2 bf16 in feat col (H-1)*64
        const int s = t >> 5, f0 = (t & 31) * 2;
        float a0 = fmaxf(candc[s * 68 + f0],     candc[2176 + s * 68 + f0]);
        float a1 = fmaxf(candc[s * 68 + f0 + 1], candc[2176 + s * 68 + f0 + 1]);
        *(unsigned*)(feat + s * BSTR + (H - 1) * 64 + f0) = pkbf(a0, a1);
    }
    // no trailing barrier
}

// ============================ main fused kernel ==============================
template<int MODE>
__global__ __launch_bounds__(1024, 1)
void caser_main(const int* __restrict__ user_id,
                const int* __restrict__ seq,
                const int* __restrict__ item_id,
                const float* __restrict__ Q,
                const float* __restrict__ Pmat,
                const float* __restrict__ Qp,
                const float* __restrict__ b_item,
                const float* __restrict__ Wv,
                const float* __restrict__ bv,
                const float* __restrict__ Wh,
                const float* __restrict__ bh,
                const float* __restrict__ Wfc,
                const float* __restrict__ bfc,
                const unsigned short* __restrict__ wfcb,
                const unsigned short* __restrict__ whb,
                float* __restrict__ out)
{
    __shared__ unsigned short xs[32 * XSTR];       // 66048 B  x = Q[seq] / zbuf4
    __shared__ unsigned short fbuf[2 * 32 * BSTR]; // 66560 B  ping-pong / candB
    __shared__ float cand[2 * 32 * 68];            // 17408 B  hconv candA
    __shared__ float wv_s[576];                    //  2304 B  Wv + bv

    const int t = threadIdx.x;
    const int lane = t & 63;
    const int w = t >> 6;                  // 0..15
    const int b0 = blockIdx.x * 32;
    const int laneA = (lane & 15) * XSTR + (lane >> 4) * 8;
    const int laneB = (lane & 15) * BSTR + (lane >> 4) * 8;
    // FC split: 4 K-quarters x 4 N-groups
    const int kh = w & 3, ng = w >> 2;
    // hconv split: sample-half x filter-16-group x j-parity
    const int hm = w & 1, hn4 = (w >> 1) & 3, pj = (w >> 3) & 1;

    // ---------------- phase 0: weights + x gather ----------------
    if (t < 576) wv_s[t] = (t < 512) ? Wv[t] : bv[t - 512];   // 1024 >= 576: safe
    #pragma unroll
    for (int k = 0; k < 8; ++k) {
        const int idx = t + k * 1024;       // 0..8191 chunks of 4 floats
        const int i = idx & 31;
        const int l = (idx >> 5) & 7;
        const int s = idx >> 8;
        const int it = seq[(b0 + s) * 8 + l];
        float4 v = *(const float4*)(Q + (size_t)it * 128 + i * 4);
        uint2 pk;
        pk.x = pkbf(v.x, v.y);
        pk.y = pkbf(v.z, v.w);
        *(uint2*)(xs + s * XSTR + l * 128 + i * 4) = pk;
    }
    __syncthreads();

    // vconv x slice -> regs: thread (sv=t>>5, dq=t&31) owns d = dq*4..+3
    const int sv = t >> 5, dq = t & 31;
    float xr[8][4];
    #pragma unroll
    for (int l = 0; l < 8; ++l) {
        bf16x4 v = *(const bf16x4*)(xs + sv * XSTR + l * 128 + dq * 4);
        #pragma unroll
        for (int i = 0; i < 4; ++i) xr[l][i] = bf2f((unsigned short)v[i]);
    }

    f32x4 FCC[2][2] = {};

    // ---------------- phase 1: vconv ∥ FC, ping-pong + B-prefetch ---------
    uint2 vc[4];
    #define VCONV_HALF(hc_)                                                    \
        {                                                                      \
            _Pragma("unroll")                                                  \
            for (int fl = 0; fl < 4; ++fl) {                                   \
                const int f = (hc_) * 4 + fl;                                  \
                const float bvv = wv_s[512 + f];                               \
                float acc[4];                                                  \
                _Pragma("unroll")                                              \
                for (int i = 0; i < 4; ++i) acc[i] = bvv;                      \
                _Pragma("unroll")                                              \
                for (int l = 0; l < 8; ++l) {                                  \
                    const float wl = wv_s[f * 8 + l];                          \
                    _Pragma("unroll")                                          \
                    for (int i = 0; i < 4; ++i)                                \
                        acc[i] = fmaf(xr[l][i], wl, acc[i]);                   \
                }                                                              \
                vc[fl].x = pkbf(fmaxf(acc[0], 0.f), fmaxf(acc[1], 0.f));       \
                vc[fl].y = pkbf(fmaxf(acc[2], 0.f), fmaxf(acc[3], 0.f));       \
            }                                                                  \
        }
    #define VSTORE(buf_)                                                       \
        {                                                                      \
            unsigned short* fb = fbuf + (buf_) * (32 * BSTR);                  \
            _Pragma("unroll")                                                  \
            for (int fl = 0; fl < 4; ++fl)                                     \
                *(uint2*)(fb + sv * BSTR + fl * 128 + dq * 4) = vc[fl];        \
        }

    bf16x8 BF0[4], BF1[4];
    #pragma unroll
    for (int ks = 0; ks < 4; ++ks) {
        const int kg = kh * 4 + ks;
        BF0[ks] = fc_bfrag<MODE>(wfcb, Wfc, kg, ng * 2,     lane);
        BF1[ks] = fc_bfrag<MODE>(wfcb, Wfc, kg, ng * 2 + 1, lane);
    }
    VCONV_HALF(0);
    VSTORE(0);
    __syncthreads();

    #pragma unroll 1
    for (int hc = 0; hc < 16; ++hc) {
        {   // FC on buf hc&1 using prefetched B-frags
            const unsigned short* fb = fbuf + (hc & 1) * (32 * BSTR);
            #pragma unroll
            for (int ks = 0; ks < 4; ++ks) {
                const int kl = kh * 4 + ks;
                bf16x8 A0 = *(const bf16x8*)(fb + laneB + kl * 32);
                bf16x8 A1 = *(const bf16x8*)(fb + 16 * BSTR + laneB + kl * 32);
                FCC[0][0] = MFMA16(A0, BF0[ks], FCC[0][0]);
                FCC[0][1] = MFMA16(A0, BF1[ks], FCC[0][1]);
                FCC[1][0] = MFMA16(A1, BF0[ks], FCC[1][0]);
                FCC[1][1] = MFMA16(A1, BF1[ks], FCC[1][1]);
            }
        }
        if (hc < 15) {
            // issue next iteration's B-frag loads; latency covered by
            // vconv VALU + VSTORE + the barrier's vmcnt(0) drain
            #pragma unroll
            for (int ks = 0; ks < 4; ++ks) {
                const int kg = (hc + 1) * 16 + kh * 4 + ks;
                BF0[ks] = fc_bfrag<MODE>(wfcb, Wfc, kg, ng * 2,     lane);
                BF1[ks] = fc_bfrag<MODE>(wfcb, Wfc, kg, ng * 2 + 1, lane);
            }
            VCONV_HALF(hc + 1);
            VSTORE((hc + 1) & 1);
        }
        __syncthreads();
    }
    #undef VCONV_HALF
    #undef VSTORE

    // ---------------- phase 2: MFMA hconv h=1..8 -> feat[32][512] ---------
    unsigned short* feat = fbuf;                      // buffer 0, cols 0..511
    float* candA = cand;
    float* candB = (float*)(fbuf + 32 * BSTR);        // dead buffer 1 (33 KB)
    hstep<1, MODE>(xs, feat, candA, whb, Wh, bh, t, lane, laneA, hm, hn4, pj);
    hstep<2, MODE>(xs, feat, candB, whb, Wh, bh, t, lane, laneA, hm, hn4, pj);
    hstep<3, MODE>(xs, feat, candA, whb, Wh, bh, t, lane, laneA, hm, hn4, pj);
    hstep<4, MODE>(xs, feat, candB, whb, Wh, bh, t, lane, laneA, hm, hn4, pj);
    hstep<5, MODE>(xs, feat, candA, whb, Wh, bh, t, lane, laneA, hm, hn4, pj);
    hstep<6, MODE>(xs, feat, candB, whb, Wh, bh, t, lane, laneA, hm, hn4, pj);
    hstep<7, MODE>(xs, feat, candA, whb, Wh, bh, t, lane, laneA, hm, hn4, pj);
    hstep<8, MODE>(xs, feat, candB, whb, Wh, bh, t, lane, laneA, hm, hn4, pj);

    // prefetch final-FC B-frags ahead of the barrier
    #pragma unroll
    for (int kgi = 0; kgi < 4; ++kgi) {
        const int kg = 256 + kh * 4 + kgi;
        BF0[kgi] = fc_bfrag<MODE>(wfcb, Wfc, kg, ng * 2,     lane);
        BF1[kgi] = fc_bfrag<MODE>(wfcb, Wfc, kg, ng * 2 + 1, lane);
    }
    __syncthreads();   // all feat columns written

    // single FC pass over hconv K=512 (kg = 256..271)
    #pragma unroll
    for (int kgi = 0; kgi < 4; ++kgi) {
        const int kloc = kh * 4 + kgi;               // 0..15
        bf16x8 A0 = *(const bf16x8*)(feat + laneB + kloc * 32);
        bf16x8 A1 = *(const bf16x8*)(feat + 16 * BSTR + laneB + kloc * 32);
        FCC[0][0] = MFMA16(A0, BF0[kgi], FCC[0][0]);
        FCC[0][1] = MFMA16(A0, BF1[kgi], FCC[0][1]);
        FCC[1][0] = MFMA16(A1, BF0[kgi], FCC[1][0]);
        FCC[1][1] = MFMA16(A1, BF1[kgi], FCC[1][1]);
    }

    // ---------------- epilogue: 4-quarter merge, relu, score --------------
    float* zbuf4 = (float*)xs;   // [4][32][132] overlay on dead xs (67584 B)
    #pragma unroll
    for (int m = 0; m < 2; ++m)
        #pragma unroll
        for (int nt = 0; nt < 2; ++nt)
            #pragma unroll
            for (int r = 0; r < 4; ++r)
                zbuf4[kh * (32 * 132) + (m * 16 + (lane >> 4) * 4 + r) * 132 +
                      ng * 32 + nt * 16 + (lane & 15)] = FCC[m][nt][r];
    __syncthreads();
    {
        const int s = t >> 5, l32 = t & 31, o0 = l32 * 4;
        const int b = b0 + s;
        const int item = item_id[b];
        const int user = user_id[b];
        const float* qp = Qp + (size_t)item * 256;
        const float* pu = Pmat + (size_t)user * 128;
        float acc2 = 0.f;
        #pragma unroll
        for (int i = 0; i < 4; ++i) {
            float z = zbuf4[s * 132 + o0 + i]
                    + zbuf4[1 * (32 * 132) + s * 132 + o0 + i]
                    + zbuf4[2 * (32 * 132) + s * 132 + o0 + i]
                    + zbuf4[3 * (32 * 132) + s * 132 + o0 + i]
                    + bfc[o0 + i];
            z = fmaxf(z, 0.f);
            acc2 = fmaf(z, qp[o0 + i], acc2);
        }
        #pragma unroll
        for (int i = 0; i < 4; ++i)
            acc2 = fmaf(pu[o0 + i], qp[128 + o0 + i], acc2);
        acc2 += __shfl_xor(acc2, 1, 32);
        acc2 += __shfl_xor(acc2, 2, 32);
        acc2 += __shfl_xor(acc2, 4, 32);
        acc2 += __shfl_xor(acc2, 8, 32);
        acc2 += __shfl_xor(acc2, 16, 32);
        if (l32 == 0) out[b] = acc2 + b_item[item];
    }
}

extern "C" void kernel_launch(void* const* d_in, const int* in_sizes, int n_in,
                              void* d_out, int out_size, void* d_ws, size_t ws_size,
                              hipStream_t stream)
{
    const int*   user_id = (const int*)  d_in[0];
    const int*   seq     = (const int*)  d_in[1];
    const int*   item_id = (const int*)  d_in[2];
    const float* Q       = (const float*)d_in[3];
    const float* Pmat    = (const float*)d_in[4];
    const float* Qp      = (const float*)d_in[5];
    const float* b_item  = (const float*)d_in[6];
    const float* Wv      = (const float*)d_in[7];
    const float* bv      = (const float*)d_in[8];
    const float* Wh      = (const float*)d_in[9];
    const float* bh      = (const float*)d_in[10];
    const float* Wfc     = (const float*)d_in[11];
    const float* bfc     = (const float*)d_in[12];
    float* out = (float*)d_out;

    unsigned short* wfcb = (unsigned short*)d_ws;
    unsigned short* whb  = wfcb + WS_FC / 2;

    if (ws_size >= WS_BOTH) {
        hipLaunchKernelGGL(caser_prep, dim3(688), dim3(256), 0, stream,
                           Wfc, Wh, wfcb, whb, 2752);
        hipLaunchKernelGGL((caser_main<2>), dim3(256), dim3(1024), 0, stream,
                           user_id, seq, item_id, Q, Pmat, Qp, b_item,
                           Wv, bv, Wh, bh, Wfc, bfc, wfcb, whb, out);
    } else if (ws_size >= WS_FC) {
        hipLaunchKernelGGL(caser_prep, dim3(544), dim3(256), 0, stream,
                           Wfc, Wh, wfcb, whb, 2176);
        hipLaunchKernelGGL((caser_main<1>), dim3(256), dim3(1024), 0, stream,
                           user_id, seq, item_id, Q, Pmat, Qp, b_item,
                           Wv, bv, Wh, bh, Wfc, bfc, wfcb, whb, out);
    } else {
        hipLaunchKernelGGL((caser_main<0>), dim3(256), dim3(1024), 0, stream,
                           user_id, seq, item_id, Q, Pmat, Qp, b_item,
                           Wv, bv, Wh, bh, Wfc, bfc,
                           (const unsigned short*)nullptr, (const unsigned short*)nullptr, out);
    }
}